// Round 11
// baseline (2402.982 us; speedup 1.0000x reference)
//
#include <hip/hip_runtime.h>

// PCEN: x (B=32, T=4000, C=128) fp32.
//   ema[t] = w*x[t] + (1-w)*ema[t-1],  ema[0] = x[0]
//   out = (x / (FLOOR + ema)^alpha + delta)^(1/root) - delta^(1/root)
//
// R15 (resubmitted R16 — broker timeout, never measured): SINGLE-PASS
// decoupled-lookback chunked scan (rocPRIM-style).
// R14 post-mortem: all top-5 = 41us harness ws-poison fills => fixed ~51us
// tax; our 3 dispatches read x TWICE (d1 + d2) at ~2.4TB/s effective and pay
// 2 dispatch gaps. Fix: one kernel reads x once. Block (b,j):
//   1. stage chunk -> LDS, local aggregate S_j = sum w(1-w)^{L-1-i} x[i]
//   2. publish S_j (agent-scope stores; flag=1 AGGREGATE) -- R12 proved
//      agent-scope atomics are XCD-coherent on this harness
//   3. lookback windows of 16 predecessors: flags+aggregates as independent
//      pipelined loads; short-circuit at newest INCLUSIVE (flag=2);
//      compose affine transforms (a,s): E_j = a*I_h + s
//   4. publish inclusive I_j = A*E_j + S_j (flag=2)
//   5. verified recurrence+epilogue from exact E_j, float4 out
// Grid (Bn, NCHUNK) => linear dispatch is j-major: predecessors of (b,j) are
// ALWAYS dispatched earlier (forward progress, rocPRIM assumption) and the
// co-resident j-window is shallow (~2048/32=64 levels).
// Flags zeroed by 16KB hipMemsetAsync (graph-safe; harness itself uses it).
// Fallback: verified R14 3-dispatch path if ws too small.

#define FLOOR_EPS 1e-12f

constexpr int Bn = 32;
constexpr int Tn = 4000;
constexpr int Cn = 128;
constexpr int NCHUNK = 125;          // 125 * 32 = 4000
constexpr int CHUNK  = 32;
constexpr int LOOKW  = 16;           // lookback window (static-indexed regs)

__device__ __forceinline__ void ag_store(float* p, float v) {
    __hip_atomic_store(p, v, __ATOMIC_RELAXED, __HIP_MEMORY_SCOPE_AGENT);
}
__device__ __forceinline__ float ag_load(const float* p) {
    return __hip_atomic_load((float*)p, __ATOMIC_RELAXED, __HIP_MEMORY_SCOPE_AGENT);
}
__device__ __forceinline__ void ag_store_flag(int* p, int v) {
    __hip_atomic_store(p, v, __ATOMIC_RELEASE, __HIP_MEMORY_SCOPE_AGENT);
}
__device__ __forceinline__ int ag_load_flag(const int* p) {
    return __hip_atomic_load((int*)p, __ATOMIC_ACQUIRE, __HIP_MEMORY_SCOPE_AGENT);
}

// ---------------- single-pass decoupled lookback ----------------
__global__ __launch_bounds__(Cn) void dlb(
    const float* __restrict__ x,
    const float* __restrict__ alpha_p,
    const float* __restrict__ delta_p,
    const float* __restrict__ root_p,
    const float* __restrict__ w_p,
    float* __restrict__ Sv,          // [Bn][NCHUNK][Cn] aggregates
    float* __restrict__ Iv,          // [Bn][NCHUNK][Cn] inclusives
    int*   __restrict__ Fl,          // [Bn][NCHUNK] flags 0/1/2
    float* __restrict__ out)
{
    __shared__ float tile[CHUNK * Cn];           // 16 KB
    const int tid = threadIdx.x;
    const int c = tid;
    const int b = blockIdx.x;                    // 0..31
    const int j = blockIdx.y;                    // 0..124
    const size_t base = ((size_t)b * Tn + (size_t)j * CHUNK) * (size_t)Cn;

    // stage x chunk (16B/lane)
    const float4* __restrict__ g4 = (const float4*)(x + base);
    float4* t4 = (float4*)tile;
    #pragma unroll
    for (int k = 0; k < 8; ++k)
        t4[k * Cn + tid] = g4[k * Cn + tid];
    __syncthreads();

    const float w   = fminf(fmaxf(w_p[c], 0.0f), 1.0f);
    const float omw = 1.0f - w;
    // A = omw^CHUNK (omw=0 -> log2=-inf -> A=0 correct; omw=1 -> A=1)
    const float A = __builtin_exp2f((float)CHUNK * __builtin_log2f(omw));

    // local aggregate: chunk transform is e -> A*e + s
    float s = 0.0f;
    #pragma unroll
    for (int k = 0; k < CHUNK; ++k)
        s = fmaf(omw, s, w * tile[k * Cn + c]);

    const int    fbase = b * NCHUNK;
    const size_t vbase = (size_t)b * NCHUNK * Cn + c;
    const size_t row   = vbase + (size_t)j * Cn;

    float E;                                     // ema state BEFORE chunk j
    if (j == 0) {
        E = x[(size_t)b * Tn * Cn + c];          // e0 = x[b,0,c]
        ag_store(&Iv[row], fmaf(A, E, s));       // I_0 = A*e0 + S_0
        __threadfence();
        __syncthreads();
        if (tid == 0) ag_store_flag(&Fl[fbase], 2);
    } else {
        // publish aggregate ASAP
        ag_store(&Sv[row], s);
        __threadfence();
        __syncthreads();
        if (tid == 0) ag_store_flag(&Fl[fbase + j], 1);

        // windowed lookback (per-thread, per-channel; flags broadcast)
        float a_acc = 1.0f, s_acc = 0.0f;
        int i = j - 1;
        bool have = false;
        while (i >= 0) {
            int lo = i - (LOOKW - 1); if (lo < 0) lo = 0;
            const int n = i - lo + 1;
            int   fl[LOOKW];
            float sv[LOOKW];
            int h;                               // newest INCLUSIVE in window
            for (;;) {
                #pragma unroll
                for (int k = 0; k < LOOKW; ++k)
                    if (k < n) fl[k] = ag_load_flag(&Fl[fbase + lo + k]);
                h = -1;
                #pragma unroll
                for (int k = 0; k < LOOKW; ++k)
                    if (k < n && fl[k] == 2) h = lo + k;   // ascending -> max
                bool retry = false;
                #pragma unroll
                for (int k = 0; k < LOOKW; ++k)
                    if (k < n && (lo + k) > h && fl[k] == 0) retry = true;
                if (!retry) break;
                __builtin_amdgcn_s_sleep(8);
            }
            // aggregates needed: indices (h, i] (independent pipelined loads)
            #pragma unroll
            for (int k = 0; k < LOOKW; ++k)
                if (k < n && (lo + k) > h)
                    sv[k] = ag_load(&Sv[vbase + (size_t)(lo + k) * Cn]);
            // compose descending q=i..(h+1): acc = acc o T_q
            #pragma unroll
            for (int k = LOOKW - 1; k >= 0; --k) {
                const int q = lo + k;
                if (k < n && q <= i && q > h) {
                    s_acc = fmaf(a_acc, sv[k], s_acc);
                    a_acc *= A;
                }
            }
            if (h >= 0) {
                const float I = ag_load(&Iv[vbase + (size_t)h * Cn]);
                E = fmaf(a_acc, I, s_acc);
                have = true;
                break;
            }
            i = lo - 1;
        }
        if (!have)                               // defensive (shouldn't hit)
            E = fmaf(a_acc, x[(size_t)b * Tn * Cn + c], s_acc);

        if (j < NCHUNK - 1) {                    // last chunk has no consumer
            ag_store(&Iv[row], fmaf(A, E, s));   // I_j = A*E_j + S_j
            __threadfence();
            __syncthreads();
            if (tid == 0) ag_store_flag(&Fl[fbase + j], 2);
        }
    }

    // ---------------- verified recurrence + epilogue ----------------
    const float alpha  = fminf(alpha_p[c], 1.0f);
    const float root   = fmaxf(root_p[c], 1.0f);
    const float delta  = delta_p[c];
    const float oor    = 1.0f / root;
    const float droot  = __builtin_exp2f(oor * __builtin_log2f(delta));
    const float nalpha = -alpha;

    float acc = E;
    #pragma unroll
    for (int k = 0; k < CHUNK; ++k) {
        const float xv = tile[k * Cn + c];       // conflict-free column
        acc = fmaf(omw, acc, w * xv);
        const float l  = __builtin_log2f(FLOOR_EPS + acc);
        const float t1 = xv * __builtin_exp2f(nalpha * l);
        tile[k * Cn + c] =
            __builtin_exp2f(oor * __builtin_log2f(t1 + delta)) - droot;
    }
    __syncthreads();

    float4* o4 = (float4*)(out + base);
    #pragma unroll
    for (int k = 0; k < 8; ++k)
        o4[k * Cn + tid] = t4[k * Cn + tid];
}

// ============ fallback: verified R14 3-dispatch path ============
__global__ __launch_bounds__(Cn) void d1_localsum(
    const float* __restrict__ x,
    const float* __restrict__ w_p,
    float* __restrict__ S)
{
    __shared__ float tile[CHUNK * Cn];
    const int tid = threadIdx.x;
    const int j = blockIdx.x;
    const int b = blockIdx.y;
    const size_t base = ((size_t)b * Tn + (size_t)j * CHUNK) * (size_t)Cn;

    const float4* __restrict__ g4 = (const float4*)(x + base);
    float4* t4 = (float4*)tile;
    #pragma unroll
    for (int k = 0; k < 8; ++k)
        t4[k * Cn + tid] = g4[k * Cn + tid];
    __syncthreads();

    const int c = tid;
    const float w   = fminf(fmaxf(w_p[c], 0.0f), 1.0f);
    const float omw = 1.0f - w;
    float s = 0.0f;
    #pragma unroll
    for (int k = 0; k < CHUNK; ++k)
        s = fmaf(omw, s, w * tile[k * Cn + c]);
    S[((size_t)b * NCHUNK + j) * Cn + c] = s;
}

__global__ __launch_bounds__(Cn) void d15_scan(
    const float* __restrict__ x,
    const float* __restrict__ w_p,
    float* __restrict__ ws)
{
    const int c = threadIdx.x;
    const int b = blockIdx.x;

    const float w   = fminf(fmaxf(w_p[c], 0.0f), 1.0f);
    const float omw = 1.0f - w;
    const float A = __builtin_exp2f((float)CHUNK * __builtin_log2f(omw));

    float e = x[(size_t)b * Tn * Cn + c];
    float* __restrict__ row = ws + (size_t)b * NCHUNK * Cn + c;

    #pragma unroll 5
    for (int jj = 0; jj < NCHUNK; ++jj) {
        const float s = row[(size_t)jj * Cn];
        row[(size_t)jj * Cn] = e;
        e = fmaf(A, e, s);
    }
}

__global__ __launch_bounds__(Cn) void d2_apply(
    const float* __restrict__ x,
    const float* __restrict__ alpha_p,
    const float* __restrict__ delta_p,
    const float* __restrict__ root_p,
    const float* __restrict__ w_p,
    const float* __restrict__ E,
    float* __restrict__ out)
{
    __shared__ float tile[CHUNK * Cn];
    const int tid = threadIdx.x;
    const int j = blockIdx.x;
    const int b = blockIdx.y;
    const size_t base = ((size_t)b * Tn + (size_t)j * CHUNK) * (size_t)Cn;

    const float4* __restrict__ g4 = (const float4*)(x + base);
    float4* t4 = (float4*)tile;
    #pragma unroll
    for (int k = 0; k < 8; ++k)
        t4[k * Cn + tid] = g4[k * Cn + tid];

    const int c = tid;
    const float w   = fminf(fmaxf(w_p[c], 0.0f), 1.0f);
    const float omw = 1.0f - w;
    const float e   = E[((size_t)b * NCHUNK + j) * Cn + c];

    const float alpha  = fminf(alpha_p[c], 1.0f);
    const float root   = fmaxf(root_p[c], 1.0f);
    const float delta  = delta_p[c];
    const float oor    = 1.0f / root;
    const float droot  = __builtin_exp2f(oor * __builtin_log2f(delta));
    const float nalpha = -alpha;
    __syncthreads();

    float acc = e;
    #pragma unroll
    for (int k = 0; k < CHUNK; ++k) {
        const float xv = tile[k * Cn + c];
        acc = fmaf(omw, acc, w * xv);
        const float l  = __builtin_log2f(FLOOR_EPS + acc);
        const float t1 = xv * __builtin_exp2f(nalpha * l);
        tile[k * Cn + c] =
            __builtin_exp2f(oor * __builtin_log2f(t1 + delta)) - droot;
    }
    __syncthreads();

    float4* o4 = (float4*)(out + base);
    #pragma unroll
    for (int k = 0; k < 8; ++k)
        o4[k * Cn + tid] = t4[k * Cn + tid];
}

extern "C" void kernel_launch(void* const* d_in, const int* in_sizes, int n_in,
                              void* d_out, int out_size, void* d_ws, size_t ws_size,
                              hipStream_t stream) {
    const float* x     = (const float*)d_in[0];
    const float* alpha = (const float*)d_in[1];
    const float* delta = (const float*)d_in[2];
    const float* root  = (const float*)d_in[3];
    const float* ew    = (const float*)d_in[4];
    float* out = (float*)d_out;

    const size_t nvals = (size_t)Bn * NCHUNK * Cn;        // 512000 floats
    const size_t ws_needed = 2 * nvals * sizeof(float)
                           + (size_t)Bn * NCHUNK * sizeof(int);  // ~4.11 MB

    if (d_ws != nullptr && ws_size >= ws_needed) {
        float* Sv = (float*)d_ws;
        float* Iv = Sv + nvals;
        int*   Fl = (int*)(Iv + nvals);
        // zero flags (16 KB; graph-safe stream op)
        hipMemsetAsync(Fl, 0, (size_t)Bn * NCHUNK * sizeof(int), stream);
        dlb<<<dim3(Bn, NCHUNK), Cn, 0, stream>>>(
            x, alpha, delta, root, ew, Sv, Iv, Fl, out);
    } else if (d_ws != nullptr && ws_size >= nvals * sizeof(float)) {
        // verified R14 path
        float* S = (float*)d_ws;
        dim3 grid(NCHUNK, Bn, 1);
        d1_localsum<<<grid, Cn, 0, stream>>>(x, ew, S);
        d15_scan<<<dim3(Bn), Cn, 0, stream>>>(x, ew, S);
        d2_apply<<<grid, Cn, 0, stream>>>(x, alpha, delta, root, ew, S, out);
    }
}

// Round 12
// 133.354 us; speedup vs baseline: 18.0195x; 18.0195x over previous
//
#include <hip/hip_runtime.h>

// PCEN: x (B=32, T=4000, C=128) fp32.
//   ema[t] = w*x[t] + (1-w)*ema[t-1],  ema[0] = x[0]
//   out = (x / (FLOOR + ema)^alpha + delta)^(1/root) - delta^(1/root)
//
// R17: TWO-dispatch, truncated-horizon chunk scan.
// Evidence so far: same-dispatch cross-block sync is 10-50x a dispatch
// boundary on this platform (R12 grid.sync: 838us @ 2% BW; R15 decoupled
// lookback: 2333us @ 1.3% VALU — per-thread acquire-flag polling storms the
// coherence fabric). Dispatch boundaries are the only cheap barrier.
// New lever is MATH: A = (1-w)^CHUNK; chunk-state E_j = sum_m A^{m-1} S_{j-m}
// (+ A^j e0). With the given w=0.04, A~0.271 -> A^16 ~ 8e-10: E_j depends on
// only the last 16 chunk aggregates to below fp32 noise (abs threshold 6.6e-2,
// current absmax 3.9e-3). So:
//   D1: per (b,j): S_j = sum_i w(1-w)^{L-1-i} x[i] -> ws[b][j][c]  (verified)
//   D2: per (b,j): E_j from a FIXED 16-row S-window (8KB, L2-resident,
//       independent preloaded loads, uniform work — fixes R13's imbalance),
//       EXACT serial-fold continuation if a=A^16 >= 1e-8 (adversarial w;
//       never taken for test inputs; j<=16 handled exactly with A^j e0),
//       then the verified recurrence + transcendental epilogue.
// No d15 dispatch (R14), no fold imbalance (R13), no intra-dispatch sync
// (R12/R15). Fallback: verified R6 3-kernel path if ws unavailable.

#define FLOOR_EPS 1e-12f

constexpr int Bn = 32;
constexpr int Tn = 4000;
constexpr int Cn = 128;
constexpr int NCHUNK = 125;          // 125 * 32 = 4000
constexpr int CHUNK  = 32;
constexpr int WIN    = 16;           // truncation window (static regs, rule #20)

// ---------------- D1: local weighted sums -> ws (verified R14 kernel) ------
__global__ __launch_bounds__(Cn) void d1_localsum(
    const float* __restrict__ x,
    const float* __restrict__ w_p,
    float* __restrict__ S)
{
    __shared__ float tile[CHUNK * Cn];           // 16 KB
    const int tid = threadIdx.x;
    const int j = blockIdx.x;
    const int b = blockIdx.y;
    const size_t base = ((size_t)b * Tn + (size_t)j * CHUNK) * (size_t)Cn;

    const float4* __restrict__ g4 = (const float4*)(x + base);
    float4* t4 = (float4*)tile;
    #pragma unroll
    for (int k = 0; k < 8; ++k)
        t4[k * Cn + tid] = g4[k * Cn + tid];
    __syncthreads();

    const int c = tid;
    const float w   = fminf(fmaxf(w_p[c], 0.0f), 1.0f);
    const float omw = 1.0f - w;
    float s = 0.0f;
    #pragma unroll
    for (int k = 0; k < CHUNK; ++k)
        s = fmaf(omw, s, w * tile[k * Cn + c]);
    S[((size_t)b * NCHUNK + j) * Cn + c] = s;    // coalesced 512B row
}

// ------- D2: truncated-window E_j + verified recurrence + epilogue --------
__global__ __launch_bounds__(Cn) void d2_trunc(
    const float* __restrict__ x,
    const float* __restrict__ alpha_p,
    const float* __restrict__ delta_p,
    const float* __restrict__ root_p,
    const float* __restrict__ w_p,
    const float* __restrict__ S,
    float* __restrict__ out)
{
    __shared__ float tile[CHUNK * Cn];           // 16 KB: x chunk then results
    const int tid = threadIdx.x;
    const int c = tid;
    const int j = blockIdx.x;
    const int b = blockIdx.y;
    const size_t base = ((size_t)b * Tn + (size_t)j * CHUNK) * (size_t)Cn;

    // stage x chunk (16B/lane) — in flight while E_j is computed
    const float4* __restrict__ g4 = (const float4*)(x + base);
    float4* t4 = (float4*)tile;
    #pragma unroll
    for (int k = 0; k < 8; ++k)
        t4[k * Cn + tid] = g4[k * Cn + tid];

    const float w   = fminf(fmaxf(w_p[c], 0.0f), 1.0f);
    const float omw = 1.0f - w;
    // A = omw^CHUNK (omw=0 -> log2=-inf -> A=0 correct; omw=1 -> A=1)
    const float A = __builtin_exp2f((float)CHUNK * __builtin_log2f(omw));

    // E_j = sum_{m=1..j} A^{m-1} S_{j-m} + A^j e0, truncated at m=WIN when
    // A^WIN is negligible; exact continuation otherwise.
    const float* __restrict__ sp = S + (size_t)b * NCHUNK * Cn + c;
    const int M1 = (j < WIN) ? j : WIN;

    float sv[WIN];                               // static-indexed (rule #20)
    #pragma unroll
    for (int k = 0; k < WIN; ++k)
        sv[k] = (k < M1) ? sp[(size_t)(j - 1 - k) * Cn] : 0.0f;

    float E = 0.0f, a = 1.0f;
    #pragma unroll
    for (int k = 0; k < WIN; ++k) {
        if (k < M1) { E = fmaf(a, sv[k], E); a *= A; }
    }
    if (j <= WIN) {
        // loop covered all of (0..j-1]; a == A^j exactly -> exact e0 term
        E = fmaf(a, x[(size_t)b * Tn * Cn + c], E);
    } else if (a >= 1e-8f) {
        // adversarial small-w: finish the fold exactly (never taken for the
        // test inputs where a = A^16 ~ 8e-10)
        for (int i = j - 1 - WIN; i >= 0; --i) {
            E = fmaf(a, sp[(size_t)i * Cn], E);
            a *= A;
        }
        E = fmaf(a, x[(size_t)b * Tn * Cn + c], E);
    }
    // else: dropped tail bounded by a < 1e-8 — far below fp32 noise/threshold

    const float alpha  = fminf(alpha_p[c], 1.0f);
    const float root   = fmaxf(root_p[c], 1.0f);
    const float delta  = delta_p[c];
    const float oor    = 1.0f / root;
    const float droot  = __builtin_exp2f(oor * __builtin_log2f(delta));
    const float nalpha = -alpha;
    __syncthreads();                             // x tile ready

    float acc = E;                               // ema state entering chunk j
    #pragma unroll
    for (int k = 0; k < CHUNK; ++k) {
        const float xv = tile[k * Cn + c];       // conflict-free column read
        acc = fmaf(omw, acc, w * xv);
        const float l  = __builtin_log2f(FLOOR_EPS + acc);
        const float t1 = xv * __builtin_exp2f(nalpha * l);
        tile[k * Cn + c] =
            __builtin_exp2f(oor * __builtin_log2f(t1 + delta)) - droot;
    }
    __syncthreads();

    float4* o4 = (float4*)(out + base);
    #pragma unroll
    for (int k = 0; k < 8; ++k)
        o4[k * Cn + tid] = t4[k * Cn + tid];
}

// ============ fallback (no ws): verified R6 3-kernel path, 133.7us ========
__global__ __launch_bounds__(Cn) void k1_localsum(
    const float* __restrict__ x,
    const float* __restrict__ w_p,
    float* __restrict__ out)
{
    __shared__ float tile[CHUNK * Cn];
    const int tid = threadIdx.x;
    const int j = blockIdx.x;
    const int b = blockIdx.y;
    const size_t base = ((size_t)b * Tn + (size_t)j * CHUNK) * (size_t)Cn;

    const float4* __restrict__ g4 = (const float4*)(x + base);
    float4* t4 = (float4*)tile;
    #pragma unroll
    for (int k = 0; k < 8; ++k)
        t4[k * Cn + tid] = g4[k * Cn + tid];
    __syncthreads();

    const int c = tid;
    const float w   = fminf(fmaxf(w_p[c], 0.0f), 1.0f);
    const float omw = 1.0f - w;
    float s = 0.0f;
    #pragma unroll
    for (int k = 0; k < CHUNK; ++k)
        s = fmaf(omw, s, w * tile[k * Cn + c]);
    out[base + Cn + c] = s;
}

__global__ __launch_bounds__(256) void k2_scan(
    const float* __restrict__ x,
    const float* __restrict__ w_p,
    float* __restrict__ out)
{
    const int wid  = (blockIdx.x * 256 + threadIdx.x) >> 6;
    const int lane = threadIdx.x & 63;
    const int b = wid >> 7;
    const int c = wid & 127;

    const float w   = fminf(fmaxf(w_p[c], 0.0f), 1.0f);
    const float omw = 1.0f - w;
    const float A = __builtin_exp2f((float)CHUNK * __builtin_log2f(omw));

    const float* __restrict__ sb = out + (size_t)b * Tn * Cn + c;
    float* __restrict__ eb       = out + (size_t)b * Tn * Cn + c;

    float s1 = sb[((size_t)lane * CHUNK + 1) * Cn];
    float a1 = A;
    const int j2 = 64 + lane;
    float s2 = (j2 < NCHUNK) ? sb[((size_t)j2 * CHUNK + 1) * Cn] : 0.0f;
    float a2 = (j2 < NCHUNK) ? A : 1.0f;

    #pragma unroll
    for (int r = 1; r < 64; r <<= 1) {
        float ts = __shfl_up(s1, r, 64);
        float ta = __shfl_up(a1, r, 64);
        if (lane >= r) { s1 = fmaf(a1, ts, s1); a1 *= ta; }
        ts = __shfl_up(s2, r, 64);
        ta = __shfl_up(a2, r, 64);
        if (lane >= r) { s2 = fmaf(a2, ts, s2); a2 *= ta; }
    }

    const float e0 = x[(size_t)b * Tn * Cn + c];
    const float E1 = fmaf(a1, e0, s1);
    const float E64 = __shfl(E1, 63, 64);
    const float E2 = fmaf(a2, E64, s2);

    if (lane == 0) eb[0] = e0;
    eb[(size_t)(lane + 1) * CHUNK * Cn] = E1;
    if (lane + 65 < NCHUNK)
        eb[(size_t)(lane + 65) * CHUNK * Cn] = E2;
}

__global__ __launch_bounds__(Cn) void k3_apply(
    const float* __restrict__ x,
    const float* __restrict__ alpha_p,
    const float* __restrict__ delta_p,
    const float* __restrict__ root_p,
    const float* __restrict__ w_p,
    float* __restrict__ out)
{
    __shared__ float tile[CHUNK * Cn];
    const int tid = threadIdx.x;
    const int j = blockIdx.x;
    const int b = blockIdx.y;
    const size_t base = ((size_t)b * Tn + (size_t)j * CHUNK) * (size_t)Cn;

    const float4* __restrict__ g4 = (const float4*)(x + base);
    float4* t4 = (float4*)tile;
    #pragma unroll
    for (int k = 0; k < 8; ++k)
        t4[k * Cn + tid] = g4[k * Cn + tid];

    const int c = tid;
    const float alpha  = fminf(alpha_p[c], 1.0f);
    const float root   = fmaxf(root_p[c], 1.0f);
    const float delta  = delta_p[c];
    const float oor    = 1.0f / root;
    const float droot  = __builtin_exp2f(oor * __builtin_log2f(delta));
    const float nalpha = -alpha;
    const float w      = fminf(fmaxf(w_p[c], 0.0f), 1.0f);
    const float omw    = 1.0f - w;

    const float E = out[base + c];
    __syncthreads();

    float acc = E;
    #pragma unroll
    for (int k = 0; k < CHUNK; ++k) {
        const float xv = tile[k * Cn + c];
        acc = fmaf(omw, acc, w * xv);
        const float l  = __builtin_log2f(FLOOR_EPS + acc);
        const float t1 = xv * __builtin_exp2f(nalpha * l);
        tile[k * Cn + c] =
            __builtin_exp2f(oor * __builtin_log2f(t1 + delta)) - droot;
    }
    __syncthreads();

    float4* o4 = (float4*)(out + base);
    #pragma unroll
    for (int k = 0; k < 8; ++k)
        o4[k * Cn + tid] = t4[k * Cn + tid];
}

extern "C" void kernel_launch(void* const* d_in, const int* in_sizes, int n_in,
                              void* d_out, int out_size, void* d_ws, size_t ws_size,
                              hipStream_t stream) {
    const float* x     = (const float*)d_in[0];
    const float* alpha = (const float*)d_in[1];
    const float* delta = (const float*)d_in[2];
    const float* root  = (const float*)d_in[3];
    const float* ew    = (const float*)d_in[4];
    float* out = (float*)d_out;

    const size_t ws_needed = (size_t)Bn * NCHUNK * Cn * sizeof(float); // 2.0 MB
    dim3 grid(NCHUNK, Bn, 1);

    if (d_ws != nullptr && ws_size >= ws_needed) {
        float* S = (float*)d_ws;
        d1_localsum<<<grid, Cn, 0, stream>>>(x, ew, S);
        d2_trunc<<<grid, Cn, 0, stream>>>(x, alpha, delta, root, ew, S, out);
    } else {
        // verified R6 path (staging inside out, coherence via dispatch
        // boundaries)
        k1_localsum<<<grid, Cn, 0, stream>>>(x, ew, out);
        k2_scan<<<dim3((Bn * Cn * 64) / 256), 256, 0, stream>>>(x, ew, out);
        k3_apply<<<grid, Cn, 0, stream>>>(x, alpha, delta, root, ew, out);
    }
}